// Round 1
// baseline (258.745 us; speedup 1.0000x reference)
//
#include <hip/hip_runtime.h>
#include <hip/hip_bf16.h>

typedef float f32x4 __attribute__((ext_vector_type(4)));
typedef __bf16 bf16x8 __attribute__((ext_vector_type(8)));

#define N 8192
#define CH 256

// ---- workspace layout (bytes) ----
static constexpr size_t OFF_T1   = 0;                          // 256 f32
static constexpr size_t OFF_T2   = 1024;                       // 256 f32
static constexpr size_t OFF_F1   = 2048;                       // 8192 f32
static constexpr size_t OFF_F2   = OFF_F1 + (size_t)N * 4;     // 8192 f32
static constexpr size_t OFF_SINV = OFF_F2 + (size_t)N * 4;     // 8192 f32
static constexpr size_t OFF_XT   = 131072;                     // 256x8192 bf16 = 4 MB
static constexpr size_t OFF_MASK = OFF_XT + (size_t)CH * N * 2;// 8192x1024 bytes = 8 MB
// total ~12.1 MB

// K1: t1[c] = sum_h w1[h]*W[h][c]; t2 likewise. One block of 256 threads.
__global__ __launch_bounds__(256) void k1_tvec(
    const float* __restrict__ W, const float* __restrict__ w1,
    const float* __restrict__ w2, float* __restrict__ t1, float* __restrict__ t2)
{
    int c = threadIdx.x;
    float a1 = 0.f, a2 = 0.f;
#pragma unroll 8
    for (int h = 0; h < CH; ++h) {
        float wv = W[h * CH + c];
        a1 = __builtin_fmaf(w1[h], wv, a1);
        a2 = __builtin_fmaf(w2[h], wv, a2);
    }
    t1[c] = a1;
    t2[c] = a2;
}

// K2: f1[i] = inlayer[i,:]·t1 + b1 ; f2[i] = inlayer[i,:]·t2 + b2. One wave per row.
__global__ __launch_bounds__(256) void k2_f(
    const float4* __restrict__ x4, const float* __restrict__ t1,
    const float* __restrict__ t2, const float* __restrict__ b1,
    const float* __restrict__ b2, float* __restrict__ f1, float* __restrict__ f2)
{
    int lane = threadIdx.x & 63, wid = threadIdx.x >> 6;
    int row = blockIdx.x * 4 + wid;
    float4 x = x4[(size_t)row * 64 + lane];
    const float4* t1v = (const float4*)t1;
    const float4* t2v = (const float4*)t2;
    float4 ta = t1v[lane], tb = t2v[lane];
    float d1 = x.x * ta.x + x.y * ta.y + x.z * ta.z + x.w * ta.w;
    float d2 = x.x * tb.x + x.y * tb.y + x.z * tb.z + x.w * tb.w;
#pragma unroll
    for (int off = 32; off; off >>= 1) {
        d1 += __shfl_down(d1, off);
        d2 += __shfl_down(d2, off);
    }
    if (lane == 0) { f1[row] = d1 + b1[0]; f2[row] = d2 + b2[0]; }
}

// KT: transpose inlayer [N][CH] f32 -> xt [CH][N] bf16. Tile 64 j x 64 ch.
__global__ __launch_bounds__(256) void kt_transpose(
    const float* __restrict__ x, unsigned short* __restrict__ xt)
{
    __shared__ unsigned short tile[64][66];
    int jb = (blockIdx.x & 127) * 64;
    int cb = (blockIdx.x >> 7) * 64;
    int t = threadIdx.x;
    int c = t & 63;
#pragma unroll
    for (int it = 0; it < 16; ++it) {
        int r = it * 4 + (t >> 6);
        float v = x[(size_t)(jb + r) * CH + cb + c];
        __hip_bfloat16 h = __float2bfloat16(v);
        tile[c][r] = *reinterpret_cast<unsigned short*>(&h);
    }
    __syncthreads();
#pragma unroll
    for (int it = 0; it < 16; ++it) {
        int cl = it * 4 + (t >> 6);
        xt[(size_t)(cb + cl) * N + jb + c] = tile[cl][c];
    }
}

__device__ __forceinline__ float lrelu_exp(float t)
{
    t = fmaxf(t, 0.01f * t);   // leaky_relu, slope 0.01 (jax default)
    return __expf(t);
}

// K3: compress adj row -> byte mask (8 cols/byte) and s[i] = sum_{j in nbr} exp(lrelu(f1+f2j)).
// One wave per row; lane handles cols [8*lane + 512*k, +8).
__global__ __launch_bounds__(256) void k3_mask(
    const int4* __restrict__ adj4, const float* __restrict__ f1,
    const float* __restrict__ f2, unsigned char* __restrict__ maskB,
    float* __restrict__ sinv)
{
    int lane = threadIdx.x & 63, wid = threadIdx.x >> 6;
    int row = blockIdx.x * 4 + wid;
    float f1r = f1[row];
    const float4* f2v = (const float4*)f2;
    size_t abase = (size_t)row * 2048;            // int4 units
    unsigned char* mrow = maskB + (size_t)row * 1024;
    float s = 0.f;
    int cnt = 0;
    for (int k = 0; k < 16; ++k) {
        int idx = k * 128 + lane * 2;
        int4 a0 = adj4[abase + idx];
        int4 a1 = adj4[abase + idx + 1];
        unsigned b = (unsigned)(a0.x > 0) | ((unsigned)(a0.y > 0) << 1)
                   | ((unsigned)(a0.z > 0) << 2) | ((unsigned)(a0.w > 0) << 3)
                   | ((unsigned)(a1.x > 0) << 4) | ((unsigned)(a1.y > 0) << 5)
                   | ((unsigned)(a1.z > 0) << 6) | ((unsigned)(a1.w > 0) << 7);
        mrow[k * 64 + lane] = (unsigned char)b;
        cnt += __popc(b);
        float4 fa = f2v[idx], fb = f2v[idx + 1];
        float e0 = lrelu_exp(f1r + fa.x);
        float e1 = lrelu_exp(f1r + fa.y);
        float e2 = lrelu_exp(f1r + fa.z);
        float e3 = lrelu_exp(f1r + fa.w);
        float e4 = lrelu_exp(f1r + fb.x);
        float e5 = lrelu_exp(f1r + fb.y);
        float e6 = lrelu_exp(f1r + fb.z);
        float e7 = lrelu_exp(f1r + fb.w);
        s += (b & 1u)   ? e0 : 0.f;
        s += (b & 2u)   ? e1 : 0.f;
        s += (b & 4u)   ? e2 : 0.f;
        s += (b & 8u)   ? e3 : 0.f;
        s += (b & 16u)  ? e4 : 0.f;
        s += (b & 32u)  ? e5 : 0.f;
        s += (b & 64u)  ? e6 : 0.f;
        s += (b & 128u) ? e7 : 0.f;
    }
#pragma unroll
    for (int off = 1; off < 64; off <<= 1) {
        s += __shfl_xor(s, off);
        cnt += __shfl_xor(cnt, off);
    }
    if (cnt == 0) {   // empty row: reference softmax degenerates to softmax over all j
        s = 0.f;
        for (int k = 0; k < 16; ++k) {
            mrow[k * 64 + lane] = 0xFFu;
            int idx = k * 128 + lane * 2;
            float4 fa = f2v[idx], fb = f2v[idx + 1];
            s += lrelu_exp(f1r + fa.x) + lrelu_exp(f1r + fa.y)
               + lrelu_exp(f1r + fa.z) + lrelu_exp(f1r + fa.w)
               + lrelu_exp(f1r + fb.x) + lrelu_exp(f1r + fb.y)
               + lrelu_exp(f1r + fb.z) + lrelu_exp(f1r + fb.w);
        }
#pragma unroll
        for (int off = 1; off < 64; off <<= 1) s += __shfl_xor(s, off);
    }
    if (lane == 0) sinv[row] = 1.0f / s;
}

// K4: out[i][c] = sinv[i] * sum_j p(i,j) * inlayer[j][c] via 16x16x32 bf16 MFMA.
// Block = 32 rows x 256 ch. 8 waves: wc in 0..3 (64-ch group), wjs in 0..1 (j-interleave),
// each wave computes 2 M-tiles x 4 N-tiles. LDS reduce across wjs at the end.
__global__ __launch_bounds__(512) void k4_pv(
    const float* __restrict__ f1, const float* __restrict__ f2,
    const unsigned char* __restrict__ maskB,
    const unsigned short* __restrict__ xt,
    const float* __restrict__ sinv, float* __restrict__ out)
{
    __shared__ float lred[4][2][4][64][4];   // 32 KB
    int tid = threadIdx.x;
    int lane = tid & 63;
    int wid = tid >> 6;
    int wc = wid & 3;
    int wjs = wid >> 2;
    int rowbase = blockIdx.x * 32;
    int r = lane & 15, q = lane >> 4;
    int chb = wc * 64;
    float f1r0 = f1[rowbase + r];
    float f1r1 = f1[rowbase + 16 + r];
    const unsigned char* mrow0 = maskB + (size_t)(rowbase + r) * 1024;
    const unsigned char* mrow1 = mrow0 + (size_t)16 * 1024;
    const float4* f2v = (const float4*)f2;
    const unsigned short* xp0 = xt + (size_t)(chb + r) * N;
    const unsigned short* xp1 = xp0 + (size_t)16 * N;
    const unsigned short* xp2 = xp0 + (size_t)32 * N;
    const unsigned short* xp3 = xp0 + (size_t)48 * N;

    f32x4 acc[2][4];
#pragma unroll
    for (int m = 0; m < 2; ++m)
#pragma unroll
        for (int nt = 0; nt < 4; ++nt) acc[m][nt] = (f32x4){0.f, 0.f, 0.f, 0.f};

    int kb = q * 8;
    for (int j0 = wjs * 32; j0 < N; j0 += 64) {
        int jo = j0 + kb;
        float4 fa = f2v[jo >> 2];
        float4 fb = f2v[(jo >> 2) + 1];
        unsigned mb0 = mrow0[(j0 >> 3) + q];
        unsigned mb1 = mrow1[(j0 >> 3) + q];
        float xs[8] = {fa.x, fa.y, fa.z, fa.w, fb.x, fb.y, fb.z, fb.w};
        bf16x8 a0, a1;
#pragma unroll
        for (int e = 0; e < 8; ++e) {
            float t0 = f1r0 + xs[e];
            t0 = fmaxf(t0, 0.01f * t0);
            float p0 = ((mb0 >> e) & 1u) ? __expf(t0) : 0.f;
            a0[e] = (__bf16)p0;
            float t1 = f1r1 + xs[e];
            t1 = fmaxf(t1, 0.01f * t1);
            float p1 = ((mb1 >> e) & 1u) ? __expf(t1) : 0.f;
            a1[e] = (__bf16)p1;
        }
        bf16x8 b0 = *reinterpret_cast<const bf16x8*>(xp0 + jo);
        bf16x8 b1 = *reinterpret_cast<const bf16x8*>(xp1 + jo);
        bf16x8 b2 = *reinterpret_cast<const bf16x8*>(xp2 + jo);
        bf16x8 b3 = *reinterpret_cast<const bf16x8*>(xp3 + jo);
        acc[0][0] = __builtin_amdgcn_mfma_f32_16x16x32_bf16(a0, b0, acc[0][0], 0, 0, 0);
        acc[0][1] = __builtin_amdgcn_mfma_f32_16x16x32_bf16(a0, b1, acc[0][1], 0, 0, 0);
        acc[0][2] = __builtin_amdgcn_mfma_f32_16x16x32_bf16(a0, b2, acc[0][2], 0, 0, 0);
        acc[0][3] = __builtin_amdgcn_mfma_f32_16x16x32_bf16(a0, b3, acc[0][3], 0, 0, 0);
        acc[1][0] = __builtin_amdgcn_mfma_f32_16x16x32_bf16(a1, b0, acc[1][0], 0, 0, 0);
        acc[1][1] = __builtin_amdgcn_mfma_f32_16x16x32_bf16(a1, b1, acc[1][1], 0, 0, 0);
        acc[1][2] = __builtin_amdgcn_mfma_f32_16x16x32_bf16(a1, b2, acc[1][2], 0, 0, 0);
        acc[1][3] = __builtin_amdgcn_mfma_f32_16x16x32_bf16(a1, b3, acc[1][3], 0, 0, 0);
    }

    if (wjs == 1) {
#pragma unroll
        for (int m = 0; m < 2; ++m)
#pragma unroll
            for (int nt = 0; nt < 4; ++nt)
                *reinterpret_cast<f32x4*>(&lred[wc][m][nt][lane][0]) = acc[m][nt];
    }
    __syncthreads();
    if (wjs == 0) {
#pragma unroll
        for (int m = 0; m < 2; ++m)
#pragma unroll
            for (int nt = 0; nt < 4; ++nt) {
                f32x4 o = *reinterpret_cast<const f32x4*>(&lred[wc][m][nt][lane][0]);
                acc[m][nt] += o;
            }
        // D layout (m89-verified): col = lane&15, row = (lane>>4)*4 + reg
#pragma unroll
        for (int m = 0; m < 2; ++m) {
#pragma unroll
            for (int reg = 0; reg < 4; ++reg) {
                int orow = rowbase + m * 16 + q * 4 + reg;
                float sv = sinv[orow];
                size_t ob = (size_t)orow * CH + chb + r;
                out[ob]      = acc[m][0][reg] * sv;
                out[ob + 16] = acc[m][1][reg] * sv;
                out[ob + 32] = acc[m][2][reg] * sv;
                out[ob + 48] = acc[m][3][reg] * sv;
            }
        }
    }
}

extern "C" void kernel_launch(void* const* d_in, const int* in_sizes, int n_in,
                              void* d_out, int out_size, void* d_ws, size_t ws_size,
                              hipStream_t stream)
{
    const float* inlayer = (const float*)d_in[0];
    const int*   adj     = (const int*)d_in[1];
    const float* W       = (const float*)d_in[2];
    const float* w1      = (const float*)d_in[3];
    const float* b1      = (const float*)d_in[4];
    const float* w2      = (const float*)d_in[5];
    const float* b2      = (const float*)d_in[6];
    float* out = (float*)d_out;

    char* ws = (char*)d_ws;
    float* t1   = (float*)(ws + OFF_T1);
    float* t2   = (float*)(ws + OFF_T2);
    float* f1   = (float*)(ws + OFF_F1);
    float* f2   = (float*)(ws + OFF_F2);
    float* sinv = (float*)(ws + OFF_SINV);
    unsigned short* xt   = (unsigned short*)(ws + OFF_XT);
    unsigned char* maskB = (unsigned char*)(ws + OFF_MASK);

    k1_tvec<<<dim3(1), dim3(256), 0, stream>>>(W, w1, w2, t1, t2);
    k2_f<<<dim3(N / 4), dim3(256), 0, stream>>>(
        (const float4*)inlayer, t1, t2, b1, b2, f1, f2);
    kt_transpose<<<dim3(512), dim3(256), 0, stream>>>(inlayer, xt);
    k3_mask<<<dim3(N / 4), dim3(256), 0, stream>>>(
        (const int4*)adj, f1, f2, maskB, sinv);
    k4_pv<<<dim3(N / 32), dim3(512), 0, stream>>>(f1, f2, maskB, xt, sinv, out);
}

// Round 2
// 184.309 us; speedup vs baseline: 1.4039x; 1.4039x over previous
//
#include <hip/hip_runtime.h>
#include <hip/hip_bf16.h>

typedef float f32x4 __attribute__((ext_vector_type(4)));
typedef __bf16 bf16x8 __attribute__((ext_vector_type(8)));

#define N 8192
#define CH 256

// ---- workspace layout (bytes) ----
static constexpr size_t OFF_P1 = 0;           // 32*256 f32 = 32 KB
static constexpr size_t OFF_P2 = 32768;       // 32*256 f32
static constexpr size_t OFF_T1 = 65536;       // 256 f32
static constexpr size_t OFF_T2 = 66560;       // 256 f32
static constexpr size_t OFF_F1 = 67584;       // 8192 f32
static constexpr size_t OFF_F2 = OFF_F1 + (size_t)N * 4;
static constexpr size_t OFF_XT = 262144;      // 256x8192 bf16 = 4 MB

// K1a: partial t-vectors over h-slices of 8. grid 32 x 256 thr.
__global__ __launch_bounds__(256) void k1a(
    const float* __restrict__ W, const float* __restrict__ w1,
    const float* __restrict__ w2, float* __restrict__ p1, float* __restrict__ p2)
{
    int b = blockIdx.x, c = threadIdx.x;
    float a1 = 0.f, a2 = 0.f;
#pragma unroll
    for (int hh = 0; hh < 8; ++hh) {
        int h = b * 8 + hh;
        float wv = W[h * CH + c];
        a1 = __builtin_fmaf(w1[h], wv, a1);
        a2 = __builtin_fmaf(w2[h], wv, a2);
    }
    p1[b * CH + c] = a1;
    p2[b * CH + c] = a2;
}

// K1b: fold 32 partials -> t1,t2. 1 block x 256 thr.
__global__ __launch_bounds__(256) void k1b(
    const float* __restrict__ p1, const float* __restrict__ p2,
    float* __restrict__ t1, float* __restrict__ t2)
{
    int c = threadIdx.x;
    float a1 = 0.f, a2 = 0.f;
#pragma unroll 8
    for (int b = 0; b < 32; ++b) { a1 += p1[b * CH + c]; a2 += p2[b * CH + c]; }
    t1[c] = a1;
    t2[c] = a2;
}

// K2: f1[i] = inlayer[i,:]·t1 + b1 ; f2[i] likewise. One wave per row.
__global__ __launch_bounds__(256) void k2_f(
    const float4* __restrict__ x4, const float* __restrict__ t1,
    const float* __restrict__ t2, const float* __restrict__ b1,
    const float* __restrict__ b2, float* __restrict__ f1, float* __restrict__ f2)
{
    int lane = threadIdx.x & 63, wid = threadIdx.x >> 6;
    int row = blockIdx.x * 4 + wid;
    float4 x = x4[(size_t)row * 64 + lane];
    const float4* t1v = (const float4*)t1;
    const float4* t2v = (const float4*)t2;
    float4 ta = t1v[lane], tb = t2v[lane];
    float d1 = x.x * ta.x + x.y * ta.y + x.z * ta.z + x.w * ta.w;
    float d2 = x.x * tb.x + x.y * tb.y + x.z * tb.z + x.w * tb.w;
#pragma unroll
    for (int off = 32; off; off >>= 1) {
        d1 += __shfl_down(d1, off);
        d2 += __shfl_down(d2, off);
    }
    if (lane == 0) { f1[row] = d1 + b1[0]; f2[row] = d2 + b2[0]; }
}

// KT: transpose inlayer [N][CH] f32 -> xt [CH][N] bf16.
__global__ __launch_bounds__(256) void kt_transpose(
    const float* __restrict__ x, unsigned short* __restrict__ xt)
{
    __shared__ unsigned short tile[64][66];
    int jb = (blockIdx.x & 127) * 64;
    int cb = (blockIdx.x >> 7) * 64;
    int t = threadIdx.x;
    int c = t & 63;
#pragma unroll
    for (int it = 0; it < 16; ++it) {
        int r = it * 4 + (t >> 6);
        float v = x[(size_t)(jb + r) * CH + cb + c];
        __hip_bfloat16 h = __float2bfloat16(v);
        tile[c][r] = *reinterpret_cast<unsigned short*>(&h);
    }
    __syncthreads();
#pragma unroll
    for (int it = 0; it < 16; ++it) {
        int cl = it * 4 + (t >> 6);
        xt[(size_t)(cb + cl) * N + jb + c] = tile[cl][c];
    }
}

// K34: fused mask+exp+rowsum+PV. Block = 32 rows x 256 ch, 8 waves, wave w
// owns j in [w*1024, (w+1)*1024). adj read exactly once; exp computed exactly
// once; acc[2][16] f32x4 per lane (32x256 per wave). LDS tree-reduce epilogue.
__global__ __launch_bounds__(512, 2) void k34_fused(
    const int* __restrict__ adj, const float* __restrict__ f1,
    const float* __restrict__ f2, const unsigned short* __restrict__ xt,
    float* __restrict__ out)
{
    __shared__ float lds[7 * 2048];     // 7 regions x 8 KB = 56 KB
    __shared__ float sred[8][2][16];
    int tid = threadIdx.x;
    int lane = tid & 63;
    int w = tid >> 6;
    int rb = blockIdx.x * 32;
    int r = lane & 15, q = lane >> 4;
    float f1r0 = f1[rb + r];
    float f1r1 = f1[rb + 16 + r];
    const int* arow0 = adj + (size_t)(rb + r) * N;
    const int* arow1 = arow0 + (size_t)16 * N;
    const unsigned short* xbase = xt + (size_t)r * N;

    f32x4 acc[2][16];
#pragma unroll
    for (int m = 0; m < 2; ++m)
#pragma unroll
        for (int nt = 0; nt < 16; ++nt) acc[m][nt] = (f32x4){0.f, 0.f, 0.f, 0.f};
    float s0 = 0.f, s1 = 0.f;
    int jbase = w * 1024 + q * 8;

    for (int it = 0; it < 32; ++it) {
        int jo = jbase + it * 32;
        int4 A0 = *(const int4*)(arow0 + jo);
        int4 A1 = *(const int4*)(arow0 + jo + 4);
        int4 B0 = *(const int4*)(arow1 + jo);
        int4 B1 = *(const int4*)(arow1 + jo + 4);
        float4 fa = *(const float4*)(f2 + jo);
        float4 fb = *(const float4*)(f2 + jo + 4);
        int av0[8] = {A0.x, A0.y, A0.z, A0.w, A1.x, A1.y, A1.z, A1.w};
        int av1[8] = {B0.x, B0.y, B0.z, B0.w, B1.x, B1.y, B1.z, B1.w};
        float fv[8] = {fa.x, fa.y, fa.z, fa.w, fb.x, fb.y, fb.z, fb.w};
        bf16x8 a0, a1;
#pragma unroll
        for (int e = 0; e < 8; ++e) {
            float t0 = f1r0 + fv[e];
            t0 = fmaxf(t0, 0.01f * t0);
            float p0 = (av0[e] > 0) ? __expf(t0) : 0.f;
            s0 += p0;
            a0[e] = (__bf16)p0;
            float t1 = f1r1 + fv[e];
            t1 = fmaxf(t1, 0.01f * t1);
            float p1 = (av1[e] > 0) ? __expf(t1) : 0.f;
            s1 += p1;
            a1[e] = (__bf16)p1;
        }
#pragma unroll
        for (int nt = 0; nt < 16; ++nt) {
            bf16x8 b = *(const bf16x8*)(xbase + (size_t)nt * 16 * N + jo);
            acc[0][nt] = __builtin_amdgcn_mfma_f32_16x16x32_bf16(a0, b, acc[0][nt], 0, 0, 0);
            acc[1][nt] = __builtin_amdgcn_mfma_f32_16x16x32_bf16(a1, b, acc[1][nt], 0, 0, 0);
        }
    }

    // row-sum: combine the 4 q-chunks (lane bits 4,5)
    s0 += __shfl_xor(s0, 16); s0 += __shfl_xor(s0, 32);
    s1 += __shfl_xor(s1, 16); s1 += __shfl_xor(s1, 32);
    if (lane < 16) { sred[w][0][lane] = s0; sred[w][1][lane] = s1; }
    __syncthreads();

    float sv[2][4] = {};
    if (w == 0) {
#pragma unroll
        for (int m = 0; m < 2; ++m)
#pragma unroll
            for (int reg = 0; reg < 4; ++reg) {
                int rr = q * 4 + reg;
                float s = 0.f;
#pragma unroll
                for (int ww = 0; ww < 8; ++ww) s += sred[ww][m][rr];
                sv[m][reg] = (s != 0.f) ? 1.0f / s : 0.f;
            }
    }

    // tree-reduce acc across 8 waves, 64-ch group per phase
    for (int g = 0; g < 4; ++g) {
        if (w >= 4) {
#pragma unroll
            for (int m = 0; m < 2; ++m)
#pragma unroll
                for (int np = 0; np < 4; ++np) {
                    int slot = (m * 4 + np) ^ (lane & 7);
                    *(f32x4*)(lds + (w - 4) * 2048 + lane * 32 + slot * 4) = acc[m][g * 4 + np];
                }
        }
        __syncthreads();
        if (w < 4) {
#pragma unroll
            for (int m = 0; m < 2; ++m)
#pragma unroll
                for (int np = 0; np < 4; ++np) {
                    int slot = (m * 4 + np) ^ (lane & 7);
                    acc[m][g * 4 + np] += *(const f32x4*)(lds + w * 2048 + lane * 32 + slot * 4);
                }
            if (w >= 1) {
#pragma unroll
                for (int m = 0; m < 2; ++m)
#pragma unroll
                    for (int np = 0; np < 4; ++np) {
                        int slot = (m * 4 + np) ^ (lane & 7);
                        *(f32x4*)(lds + (3 + w) * 2048 + lane * 32 + slot * 4) = acc[m][g * 4 + np];
                    }
            }
        }
        __syncthreads();
        if (w == 0) {
#pragma unroll
            for (int m = 0; m < 2; ++m)
#pragma unroll
                for (int np = 0; np < 4; ++np) {
                    int slot = (m * 4 + np) ^ (lane & 7);
                    f32x4 v = acc[m][g * 4 + np];
#pragma unroll
                    for (int ww = 1; ww < 4; ++ww)
                        v += *(const f32x4*)(lds + (3 + ww) * 2048 + lane * 32 + slot * 4);
#pragma unroll
                    for (int reg = 0; reg < 4; ++reg) {
                        int row = rb + m * 16 + q * 4 + reg;
                        int col = g * 64 + np * 16 + r;
                        out[(size_t)row * CH + col] = v[reg] * sv[m][reg];
                    }
                }
        }
        __syncthreads();
    }
}

extern "C" void kernel_launch(void* const* d_in, const int* in_sizes, int n_in,
                              void* d_out, int out_size, void* d_ws, size_t ws_size,
                              hipStream_t stream)
{
    const float* inlayer = (const float*)d_in[0];
    const int*   adj     = (const int*)d_in[1];
    const float* W       = (const float*)d_in[2];
    const float* w1      = (const float*)d_in[3];
    const float* b1      = (const float*)d_in[4];
    const float* w2      = (const float*)d_in[5];
    const float* b2      = (const float*)d_in[6];
    float* out = (float*)d_out;

    char* ws = (char*)d_ws;
    float* p1 = (float*)(ws + OFF_P1);
    float* p2 = (float*)(ws + OFF_P2);
    float* t1 = (float*)(ws + OFF_T1);
    float* t2 = (float*)(ws + OFF_T2);
    float* f1 = (float*)(ws + OFF_F1);
    float* f2 = (float*)(ws + OFF_F2);
    unsigned short* xt = (unsigned short*)(ws + OFF_XT);

    k1a<<<dim3(32), dim3(256), 0, stream>>>(W, w1, w2, p1, p2);
    kt_transpose<<<dim3(512), dim3(256), 0, stream>>>(inlayer, xt);
    k1b<<<dim3(1), dim3(256), 0, stream>>>(p1, p2, t1, t2);
    k2_f<<<dim3(N / 4), dim3(256), 0, stream>>>(
        (const float4*)inlayer, t1, t2, b1, b2, f1, f2);
    k34_fused<<<dim3(N / 32), dim3(512), 0, stream>>>(adj, f1, f2, xt, out);
}

// Round 3
// 164.703 us; speedup vs baseline: 1.5710x; 1.1190x over previous
//
#include <hip/hip_runtime.h>
#include <hip/hip_bf16.h>

typedef float f32x4 __attribute__((ext_vector_type(4)));
typedef __bf16 bf16x8 __attribute__((ext_vector_type(8)));

#define N 8192
#define CH 256
#define JT 256
#define NTILES (N / JT)

// ---- workspace layout (bytes) ----
static constexpr size_t OFF_P1 = 0;           // 32*256 f32
static constexpr size_t OFF_P2 = 32768;
static constexpr size_t OFF_T1 = 65536;       // 256 f32
static constexpr size_t OFF_T2 = 66560;
static constexpr size_t OFF_F1 = 67584;       // 8192 f32
static constexpr size_t OFF_F2 = OFF_F1 + (size_t)N * 4;
static constexpr size_t OFF_XT = 262144;      // 256x8192 bf16 = 4 MB

// K1a: partial t-vectors over h-slices of 8. grid 32 x 256 thr.
__global__ __launch_bounds__(256) void k1a(
    const float* __restrict__ W, const float* __restrict__ w1,
    const float* __restrict__ w2, float* __restrict__ p1, float* __restrict__ p2)
{
    int b = blockIdx.x, c = threadIdx.x;
    float a1 = 0.f, a2 = 0.f;
#pragma unroll
    for (int hh = 0; hh < 8; ++hh) {
        int h = b * 8 + hh;
        float wv = W[h * CH + c];
        a1 = __builtin_fmaf(w1[h], wv, a1);
        a2 = __builtin_fmaf(w2[h], wv, a2);
    }
    p1[b * CH + c] = a1;
    p2[b * CH + c] = a2;
}

// K1b: fold 32 partials -> t1,t2.
__global__ __launch_bounds__(256) void k1b(
    const float* __restrict__ p1, const float* __restrict__ p2,
    float* __restrict__ t1, float* __restrict__ t2)
{
    int c = threadIdx.x;
    float a1 = 0.f, a2 = 0.f;
#pragma unroll 8
    for (int b = 0; b < 32; ++b) { a1 += p1[b * CH + c]; a2 += p2[b * CH + c]; }
    t1[c] = a1;
    t2[c] = a2;
}

// K2: f1[i] = inlayer[i,:]·t1 + b1 ; f2[i] likewise. One wave per row.
__global__ __launch_bounds__(256) void k2_f(
    const float4* __restrict__ x4, const float* __restrict__ t1,
    const float* __restrict__ t2, const float* __restrict__ b1,
    const float* __restrict__ b2, float* __restrict__ f1, float* __restrict__ f2)
{
    int lane = threadIdx.x & 63, wid = threadIdx.x >> 6;
    int row = blockIdx.x * 4 + wid;
    float4 x = x4[(size_t)row * 64 + lane];
    const float4* t1v = (const float4*)t1;
    const float4* t2v = (const float4*)t2;
    float4 ta = t1v[lane], tb = t2v[lane];
    float d1 = x.x * ta.x + x.y * ta.y + x.z * ta.z + x.w * ta.w;
    float d2 = x.x * tb.x + x.y * tb.y + x.z * tb.z + x.w * tb.w;
#pragma unroll
    for (int off = 32; off; off >>= 1) {
        d1 += __shfl_down(d1, off);
        d2 += __shfl_down(d2, off);
    }
    if (lane == 0) { f1[row] = d1 + b1[0]; f2[row] = d2 + b2[0]; }
}

// KT: transpose inlayer [N][CH] f32 -> xt [CH][N] bf16.
__global__ __launch_bounds__(256) void kt_transpose(
    const float* __restrict__ x, unsigned short* __restrict__ xt)
{
    __shared__ unsigned short tile[64][66];
    int jb = (blockIdx.x & 127) * 64;
    int cb = (blockIdx.x >> 7) * 64;
    int t = threadIdx.x;
    int c = t & 63;
#pragma unroll
    for (int it = 0; it < 16; ++it) {
        int r = it * 4 + (t >> 6);
        float v = x[(size_t)(jb + r) * CH + cb + c];
        __hip_bfloat16 h = __float2bfloat16(v);
        tile[c][r] = *reinterpret_cast<unsigned short*>(&h);
    }
    __syncthreads();
#pragma unroll
    for (int it = 0; it < 16; ++it) {
        int cl = it * 4 + (t >> 6);
        xt[(size_t)(cb + cl) * N + jb + c] = tile[cl][c];
    }
}

// K34 v3: producer/consumer via double-buffered LDS P-tile.
// Block = 32 rows x 256 ch, 1024 threads (16 waves).
// Phase A (all threads): stage adj+f2 regs early (T14), exp -> P[next] late.
// Phase B: wave w = (cg 0..7, js 0..1): 2 m-tiles x 2 n-tiles x 4 k-steps MFMA.
// P LDS layout: 16B unit u = ((m*8+ks)*64 + q*16 + r) ^ ks  -> canonical
// conflict-free ds_read_b128 (lane-permuted contiguous).
__global__ __launch_bounds__(1024, 4) void k34_fused(
    const int* __restrict__ adj, const float* __restrict__ f1,
    const float* __restrict__ f2, const unsigned short* __restrict__ xt,
    float* __restrict__ out)
{
    __shared__ __align__(16) unsigned short P[2][8192];   // 2 x 16 KB
    __shared__ f32x4 cred[8][2][2][64];                   // 16 KB
    __shared__ float srow[32];

    const int tid = threadIdx.x;
    const int lane = tid & 63;
    const int w = tid >> 6;
    const int r = lane & 15, q = lane >> 4;
    const int rb = blockIdx.x * 32;

    // ---- phase-A role: row = tid>>5, 8 j's starting at (tid&31)*8 ----
    const int arow_ = tid >> 5;              // 0..31
    const int am = arow_ >> 4;
    const int ar = arow_ & 15;
    const int ajo = (tid & 31) * 8;          // 0..248
    const int aks = ajo >> 5;
    const int wunit = (((am * 8 + aks) * 64) + ((ajo >> 3) & 3) * 16 + ar) ^ aks;
    const float f1r = f1[rb + arow_];
    const int* arow = adj + (size_t)(rb + arow_) * N + ajo;
    const float* f2p = f2 + ajo;

    // ---- phase-B role ----
    const int cg = w & 7;                    // 32-ch group
    const int js = w >> 3;                   // k-half
    const unsigned short* xb0 = xt + (size_t)(cg * 32 + r) * N + js * 128 + q * 8;
    const unsigned short* xb1 = xb0 + (size_t)16 * N;

    f32x4 acc[2][2];
#pragma unroll
    for (int m = 0; m < 2; ++m)
#pragma unroll
        for (int nt = 0; nt < 2; ++nt) acc[m][nt] = (f32x4){0.f, 0.f, 0.f, 0.f};
    float s_acc = 0.f;

    int4 sa0, sa1;
    float4 sg0, sg1;

    auto stage = [&](int jt) {
        sa0 = *(const int4*)(arow + jt);
        sa1 = *(const int4*)(arow + jt + 4);
        sg0 = *(const float4*)(f2p + jt);
        sg1 = *(const float4*)(f2p + jt + 4);
    };
    auto exp_write = [&](int buf) {
        int av[8] = {sa0.x, sa0.y, sa0.z, sa0.w, sa1.x, sa1.y, sa1.z, sa1.w};
        float gv[8] = {sg0.x, sg0.y, sg0.z, sg0.w, sg1.x, sg1.y, sg1.z, sg1.w};
        bf16x8 pk;
#pragma unroll
        for (int e = 0; e < 8; ++e) {
            float tt = f1r + gv[e];
            tt = fmaxf(tt, 0.01f * tt);
            float p = (av[e] > 0) ? __expf(tt) : 0.f;
            s_acc += p;
            pk[e] = (__bf16)p;
        }
        *reinterpret_cast<bf16x8*>(&P[buf][(size_t)wunit * 8]) = pk;
    };

    // prologue
    stage(0);
    exp_write(0);
    __syncthreads();

    for (int t = 0; t < NTILES; ++t) {
        const int jt = t * JT;
        if (t + 1 < NTILES) stage(jt + JT);          // issue loads early (T14)

        const unsigned short* pb = &P[t & 1][0];
#pragma unroll
        for (int kk = 0; kk < 4; ++kk) {
            const int ks = js * 4 + kk;
            bf16x8 A0 = *reinterpret_cast<const bf16x8*>(pb + (size_t)((ks * 64 + (lane ^ ks)) * 8));
            bf16x8 A1 = *reinterpret_cast<const bf16x8*>(pb + (size_t)(((8 + ks) * 64 + (lane ^ ks)) * 8));
            bf16x8 B0 = *reinterpret_cast<const bf16x8*>(xb0 + jt + kk * 32);
            bf16x8 B1 = *reinterpret_cast<const bf16x8*>(xb1 + jt + kk * 32);
            acc[0][0] = __builtin_amdgcn_mfma_f32_16x16x32_bf16(A0, B0, acc[0][0], 0, 0, 0);
            acc[0][1] = __builtin_amdgcn_mfma_f32_16x16x32_bf16(A0, B1, acc[0][1], 0, 0, 0);
            acc[1][0] = __builtin_amdgcn_mfma_f32_16x16x32_bf16(A1, B0, acc[1][0], 0, 0, 0);
            acc[1][1] = __builtin_amdgcn_mfma_f32_16x16x32_bf16(A1, B1, acc[1][1], 0, 0, 0);
        }
        if (t + 1 < NTILES) exp_write((t + 1) & 1);  // write-late
        __syncthreads();
    }

    // ---- row-sum: each half-wave (32 lanes) holds one row's partials ----
#pragma unroll
    for (int off = 1; off < 32; off <<= 1) s_acc += __shfl_xor(s_acc, off);
    if ((lane & 31) == 0) srow[w * 2 + (lane >> 5)] = s_acc;

    if (js == 1) {
        cred[cg][0][0][lane] = acc[0][0];
        cred[cg][0][1][lane] = acc[0][1];
        cred[cg][1][0][lane] = acc[1][0];
        cred[cg][1][1][lane] = acc[1][1];
    }
    __syncthreads();

    if (js == 0) {
        acc[0][0] += cred[cg][0][0][lane];
        acc[0][1] += cred[cg][0][1][lane];
        acc[1][0] += cred[cg][1][0][lane];
        acc[1][1] += cred[cg][1][1][lane];
        float sv[2][4];
#pragma unroll
        for (int m = 0; m < 2; ++m)
#pragma unroll
            for (int reg = 0; reg < 4; ++reg) {
                float s = srow[m * 16 + q * 4 + reg];
                sv[m][reg] = (s != 0.f) ? 1.0f / s : 0.f;
            }
#pragma unroll
        for (int m = 0; m < 2; ++m)
#pragma unroll
            for (int nt = 0; nt < 2; ++nt)
#pragma unroll
                for (int reg = 0; reg < 4; ++reg) {
                    int row = rb + m * 16 + q * 4 + reg;
                    int col = cg * 32 + nt * 16 + r;
                    out[(size_t)row * CH + col] = acc[m][nt][reg] * sv[m][reg];
                }
    }
}

extern "C" void kernel_launch(void* const* d_in, const int* in_sizes, int n_in,
                              void* d_out, int out_size, void* d_ws, size_t ws_size,
                              hipStream_t stream)
{
    const float* inlayer = (const float*)d_in[0];
    const int*   adj     = (const int*)d_in[1];
    const float* W       = (const float*)d_in[2];
    const float* w1      = (const float*)d_in[3];
    const float* b1      = (const float*)d_in[4];
    const float* w2      = (const float*)d_in[5];
    const float* b2      = (const float*)d_in[6];
    float* out = (float*)d_out;

    char* ws = (char*)d_ws;
    float* p1 = (float*)(ws + OFF_P1);
    float* p2 = (float*)(ws + OFF_P2);
    float* t1 = (float*)(ws + OFF_T1);
    float* t2 = (float*)(ws + OFF_T2);
    float* f1 = (float*)(ws + OFF_F1);
    float* f2 = (float*)(ws + OFF_F2);
    unsigned short* xt = (unsigned short*)(ws + OFF_XT);

    k1a<<<dim3(32), dim3(256), 0, stream>>>(W, w1, w2, p1, p2);
    kt_transpose<<<dim3(512), dim3(256), 0, stream>>>(inlayer, xt);
    k1b<<<dim3(1), dim3(256), 0, stream>>>(p1, p2, t1, t2);
    k2_f<<<dim3(N / 4), dim3(256), 0, stream>>>(
        (const float4*)inlayer, t1, t2, b1, b2, f1, f2);
    k34_fused<<<dim3(N / 32), dim3(1024), 0, stream>>>(adj, f1, f2, xt, out);
}

// Round 4
// 140.487 us; speedup vs baseline: 1.8418x; 1.1724x over previous
//
#include <hip/hip_runtime.h>
#include <hip/hip_bf16.h>

typedef float f32x4 __attribute__((ext_vector_type(4)));
typedef __bf16 bf16x8 __attribute__((ext_vector_type(8)));

#define N 8192
#define CH 256
#define NJC 4            // j-chunks
#define JCW (N / NJC)    // 2048 j per chunk
#define JT 128           // j per tile
#define NT (JCW / JT)    // 16 tiles
#define BM 64            // rows per block

// ---- workspace layout (bytes) ----
static constexpr size_t OFF_P1 = 0;
static constexpr size_t OFF_P2 = 32768;
static constexpr size_t OFF_T1 = 65536;
static constexpr size_t OFF_T2 = 66560;
static constexpr size_t OFF_F1 = 67584;
static constexpr size_t OFF_F2 = OFF_F1 + (size_t)N * 4;
static constexpr size_t OFF_XT = 262144;                       // 4 MB
static constexpr size_t OFF_SP = OFF_XT + (size_t)CH * N * 2;  // 4x8192 f32
static constexpr size_t OFF_PV = OFF_SP + (size_t)NJC * N * 4; // 3x8 MB
// total ~28.4 MB

// K1a: partial t-vectors over h-slices of 8.
__global__ __launch_bounds__(256) void k1a(
    const float* __restrict__ W, const float* __restrict__ w1,
    const float* __restrict__ w2, float* __restrict__ p1, float* __restrict__ p2)
{
    int b = blockIdx.x, c = threadIdx.x;
    float a1 = 0.f, a2 = 0.f;
#pragma unroll
    for (int hh = 0; hh < 8; ++hh) {
        int h = b * 8 + hh;
        float wv = W[h * CH + c];
        a1 = __builtin_fmaf(w1[h], wv, a1);
        a2 = __builtin_fmaf(w2[h], wv, a2);
    }
    p1[b * CH + c] = a1;
    p2[b * CH + c] = a2;
}

// K1b: fold 32 partials -> t1,t2.
__global__ __launch_bounds__(256) void k1b(
    const float* __restrict__ p1, const float* __restrict__ p2,
    float* __restrict__ t1, float* __restrict__ t2)
{
    int c = threadIdx.x;
    float a1 = 0.f, a2 = 0.f;
#pragma unroll 8
    for (int b = 0; b < 32; ++b) { a1 += p1[b * CH + c]; a2 += p2[b * CH + c]; }
    t1[c] = a1;
    t2[c] = a2;
}

// K2: f1[i] = inlayer[i,:]·t1 + b1 ; f2[i] likewise. One wave per row.
__global__ __launch_bounds__(256) void k2_f(
    const float4* __restrict__ x4, const float* __restrict__ t1,
    const float* __restrict__ t2, const float* __restrict__ b1,
    const float* __restrict__ b2, float* __restrict__ f1, float* __restrict__ f2)
{
    int lane = threadIdx.x & 63, wid = threadIdx.x >> 6;
    int row = blockIdx.x * 4 + wid;
    float4 x = x4[(size_t)row * 64 + lane];
    const float4* t1v = (const float4*)t1;
    const float4* t2v = (const float4*)t2;
    float4 ta = t1v[lane], tb = t2v[lane];
    float d1 = x.x * ta.x + x.y * ta.y + x.z * ta.z + x.w * ta.w;
    float d2 = x.x * tb.x + x.y * tb.y + x.z * tb.z + x.w * tb.w;
#pragma unroll
    for (int off = 32; off; off >>= 1) {
        d1 += __shfl_down(d1, off);
        d2 += __shfl_down(d2, off);
    }
    if (lane == 0) { f1[row] = d1 + b1[0]; f2[row] = d2 + b2[0]; }
}

// KT: transpose inlayer [N][CH] f32 -> xt [CH][N] bf16.
__global__ __launch_bounds__(256) void kt_transpose(
    const float* __restrict__ x, unsigned short* __restrict__ xt)
{
    __shared__ unsigned short tile[64][66];
    int jb = (blockIdx.x & 127) * 64;
    int cb = (blockIdx.x >> 7) * 64;
    int t = threadIdx.x;
    int c = t & 63;
#pragma unroll
    for (int it = 0; it < 16; ++it) {
        int r = it * 4 + (t >> 6);
        float v = x[(size_t)(jb + r) * CH + cb + c];
        __hip_bfloat16 h = __float2bfloat16(v);
        tile[c][r] = *reinterpret_cast<unsigned short*>(&h);
    }
    __syncthreads();
#pragma unroll
    for (int it = 0; it < 16; ++it) {
        int cl = it * 4 + (t >> 6);
        xt[(size_t)(cb + cl) * N + jb + c] = tile[cl][c];
    }
}

// K34 v4: M=64 rows x 2048-j chunk per block. 512 threads (8 waves = 8 ch-groups
// of 32). 2-deep reg prefetch of adj; P double-buffered in LDS with XOR-swizzled
// 16B units; each wave reduces full chunk-j for its ch slice (no cross-wave acc
// reduce). Partial PV + row-sums written per chunk; k5 combines.
__global__ __launch_bounds__(512, 4) void k34_fused(
    const int* __restrict__ adj, const float* __restrict__ f1,
    const float* __restrict__ f2, const unsigned short* __restrict__ xt,
    float* __restrict__ pv0, float* __restrict__ pvx, float* __restrict__ s_part)
{
    __shared__ __align__(16) unsigned short P[2][BM * JT];   // 2 x 16 KB

    const int tid = threadIdx.x;
    const int lane = tid & 63;
    const int w = tid >> 6;              // ch-group 0..7
    const int r = lane & 15, q = lane >> 4;
    const int bid = blockIdx.x;
    const int jc = bid & 3;              // j-chunk; pinned per XCD (bid%8 = XCD)
    const int rb = (bid >> 2) * BM;
    const int jbase = jc * JCW;

    // producer role: row = tid>>3 (0..63), 16 j's at (tid&7)*16
    const int prow = tid >> 3;
    const int pjo = (tid & 7) * 16;
    const float f1r = f1[rb + prow];
    const int* aptr = adj + (size_t)(rb + prow) * N + jbase + pjo;
    const float* fptr = f2 + jbase + pjo;
    const int cu0 = (tid & 7) * 2;
    const int wu0 = prow * 16 + (cu0 ^ (prow & 15));
    const int wu1 = prow * 16 + ((cu0 + 1) ^ (prow & 15));

    // consumer role
    const unsigned short* xb0 = xt + (size_t)(w * 32 + r) * N + jbase + q * 8;
    const unsigned short* xb1 = xb0 + (size_t)16 * N;

    f32x4 acc[4][2];
#pragma unroll
    for (int mt = 0; mt < 4; ++mt)
#pragma unroll
        for (int nt = 0; nt < 2; ++nt) acc[mt][nt] = (f32x4){0.f, 0.f, 0.f, 0.f};
    float s_acc = 0.f;

    int4 RA0, RA1, RA2, RA3, RB0, RB1, RB2, RB3;
    float4 F0, F1, F2, F3;

#define LOAD_A(R0, R1, R2, R3, t)                                   \
    { const int4* p_ = (const int4*)(aptr + (t) * JT);              \
      R0 = p_[0]; R1 = p_[1]; R2 = p_[2]; R3 = p_[3]; }
#define LOAD_F(t)                                                   \
    { const float4* p_ = (const float4*)(fptr + (t) * JT);          \
      F0 = p_[0]; F1 = p_[1]; F2 = p_[2]; F3 = p_[3]; }
#define EXPW(R0, R1, R2, R3, buf)                                   \
    { int av[16] = {R0.x, R0.y, R0.z, R0.w, R1.x, R1.y, R1.z, R1.w, \
                    R2.x, R2.y, R2.z, R2.w, R3.x, R3.y, R3.z, R3.w};\
      float gv[16] = {F0.x, F0.y, F0.z, F0.w, F1.x, F1.y, F1.z, F1.w,\
                      F2.x, F2.y, F2.z, F2.w, F3.x, F3.y, F3.z, F3.w};\
      bf16x8 pk0, pk1;                                              \
      _Pragma("unroll")                                             \
      for (int e = 0; e < 16; ++e) {                                \
          float tt = f1r + gv[e];                                   \
          tt = fmaxf(tt, 0.01f * tt);                               \
          float p = (av[e] > 0) ? __expf(tt) : 0.f;                 \
          s_acc += p;                                               \
          if (e < 8) pk0[e] = (__bf16)p; else pk1[e - 8] = (__bf16)p;\
      }                                                             \
      *reinterpret_cast<bf16x8*>(&P[buf][wu0 * 8]) = pk0;           \
      *reinterpret_cast<bf16x8*>(&P[buf][wu1 * 8]) = pk1; }
#define MFMA_TILE(t, buf)                                           \
    { const unsigned short* pb_ = &P[buf][0];                       \
      _Pragma("unroll")                                             \
      for (int kk = 0; kk < 4; ++kk) {                              \
          bf16x8 B0 = *(const bf16x8*)(xb0 + (size_t)(t) * JT + kk * 32); \
          bf16x8 B1 = *(const bf16x8*)(xb1 + (size_t)(t) * JT + kk * 32); \
          _Pragma("unroll")                                         \
          for (int mt = 0; mt < 4; ++mt) {                          \
              int u_ = (mt * 16 + r) * 16 + ((kk * 4 + q) ^ r);     \
              bf16x8 A = *(const bf16x8*)(pb_ + (size_t)u_ * 8);    \
              acc[mt][0] = __builtin_amdgcn_mfma_f32_16x16x32_bf16(A, B0, acc[mt][0], 0, 0, 0); \
              acc[mt][1] = __builtin_amdgcn_mfma_f32_16x16x32_bf16(A, B1, acc[mt][1], 0, 0, 0); \
          }                                                         \
      } }

    // prologue
    LOAD_A(RA0, RA1, RA2, RA3, 0);
    LOAD_A(RB0, RB1, RB2, RB3, 1);
    LOAD_F(0);
    EXPW(RA0, RA1, RA2, RA3, 0);
    __syncthreads();

    for (int t = 0; t < NT; t += 2) {
        // even sub-iter: consume P[0]; prefetch adj t+2 into RA; exp RB -> P[1]
        if (t + 2 < NT) LOAD_A(RA0, RA1, RA2, RA3, t + 2);
        LOAD_F(t + 1);
        MFMA_TILE(t, 0);
        EXPW(RB0, RB1, RB2, RB3, 1);
        __syncthreads();
        // odd sub-iter: consume P[1]; prefetch adj t+3 into RB; exp RA -> P[0]
        if (t + 3 < NT) LOAD_A(RB0, RB1, RB2, RB3, t + 3);
        if (t + 2 < NT) LOAD_F(t + 2);
        MFMA_TILE(t + 1, 1);
        if (t + 2 < NT) EXPW(RA0, RA1, RA2, RA3, 0);
        __syncthreads();
    }

    // row-sum partial: 8 threads per row (consecutive lanes)
    s_acc += __shfl_xor(s_acc, 1);
    s_acc += __shfl_xor(s_acc, 2);
    s_acc += __shfl_xor(s_acc, 4);
    if ((lane & 7) == 0) s_part[jc * N + rb + prow] = s_acc;

    // write PV partial. D layout: col = lane&15, row = (lane>>4)*4 + reg
    float* dst = (jc == 0) ? pv0 : (pvx + (size_t)(jc - 1) * N * CH);
#pragma unroll
    for (int mt = 0; mt < 4; ++mt)
#pragma unroll
        for (int nt = 0; nt < 2; ++nt)
#pragma unroll
            for (int reg = 0; reg < 4; ++reg) {
                int row = rb + mt * 16 + q * 4 + reg;
                int col = w * 32 + nt * 16 + r;
                dst[(size_t)row * CH + col] = acc[mt][nt][reg];
            }
#undef LOAD_A
#undef LOAD_F
#undef EXPW
#undef MFMA_TILE
}

// K5: out[i][c] = (sum_k pv_k) * inv(sum_k s_k). pv0 lives in d_out.
__global__ __launch_bounds__(256) void k5_reduce(
    const float* __restrict__ pvx, const float* __restrict__ s_part,
    float* __restrict__ out)
{
    int g = blockIdx.x * 256 + threadIdx.x;      // float4 index
    int row = g >> 6;
    float s = s_part[row] + s_part[N + row] + s_part[2 * N + row] + s_part[3 * N + row];
    float inv = (s != 0.f) ? 1.0f / s : 0.f;
    float4* out4 = (float4*)out;
    const float4* p1 = (const float4*)pvx;
    const float4* p2 = p1 + (size_t)N * CH / 4;
    const float4* p3 = p2 + (size_t)N * CH / 4;
    float4 v = out4[g];
    float4 a = p1[g], b = p2[g], c = p3[g];
    v.x = (v.x + a.x + b.x + c.x) * inv;
    v.y = (v.y + a.y + b.y + c.y) * inv;
    v.z = (v.z + a.z + b.z + c.z) * inv;
    v.w = (v.w + a.w + b.w + c.w) * inv;
    out4[g] = v;
}

extern "C" void kernel_launch(void* const* d_in, const int* in_sizes, int n_in,
                              void* d_out, int out_size, void* d_ws, size_t ws_size,
                              hipStream_t stream)
{
    const float* inlayer = (const float*)d_in[0];
    const int*   adj     = (const int*)d_in[1];
    const float* W       = (const float*)d_in[2];
    const float* w1      = (const float*)d_in[3];
    const float* b1      = (const float*)d_in[4];
    const float* w2      = (const float*)d_in[5];
    const float* b2      = (const float*)d_in[6];
    float* out = (float*)d_out;

    char* ws = (char*)d_ws;
    float* p1 = (float*)(ws + OFF_P1);
    float* p2 = (float*)(ws + OFF_P2);
    float* t1 = (float*)(ws + OFF_T1);
    float* t2 = (float*)(ws + OFF_T2);
    float* f1 = (float*)(ws + OFF_F1);
    float* f2 = (float*)(ws + OFF_F2);
    unsigned short* xt = (unsigned short*)(ws + OFF_XT);
    float* s_part = (float*)(ws + OFF_SP);
    float* pvx = (float*)(ws + OFF_PV);

    k1a<<<dim3(32), dim3(256), 0, stream>>>(W, w1, w2, p1, p2);
    kt_transpose<<<dim3(512), dim3(256), 0, stream>>>(inlayer, xt);
    k1b<<<dim3(1), dim3(256), 0, stream>>>(p1, p2, t1, t2);
    k2_f<<<dim3(N / 4), dim3(256), 0, stream>>>(
        (const float4*)inlayer, t1, t2, b1, b2, f1, f2);
    k34_fused<<<dim3((N / BM) * NJC), dim3(512), 0, stream>>>(
        adj, f1, f2, xt, out, pvx, s_part);
    k5_reduce<<<dim3(N * CH / 4 / 256), dim3(256), 0, stream>>>(pvx, s_part, out);
}